// Round 14
// baseline (3013.172 us; speedup 1.0000x reference)
//
#include <hip/hip_runtime.h>
#include <math.h>

#define NB 256
#define TT 64
#define DD 1024
#define HH 1024
#define FOURH 4096
#define KTOT 3072
#define KT16 192                  // K-tiles of 16
#define P1 (NB * FOURH)           // one partial plane (f32 elems)
#define NZ 4                      // K-split planes

#define AF_LVL 786432ull          // 8 mt * 192 kt * 512
#define BF_LVL 12582912ull        // 128 ct * 192 kt * 512
#define SPLIT_SCALE 2048.0f
#define INV_SPLIT (1.0f / 2048.0f)

typedef _Float16 f16x8 __attribute__((ext_vector_type(8)));
typedef float f32x16 __attribute__((ext_vector_type(16)));

__device__ __forceinline__ unsigned short f2h(float f) {
    _Float16 h = (_Float16)f;
    unsigned short u;
    __builtin_memcpy(&u, &h, 2);
    return u;
}
__device__ __forceinline__ float h2f(unsigned short u) {
    _Float16 h;
    __builtin_memcpy(&h, &u, 2);
    return (float)h;
}
// 2-way fp16 split; lo pre-scaled by 2^11 to stay out of subnormal range
__device__ __forceinline__ void split2(float f, unsigned short& hi, unsigned short& lo) {
    hi = f2h(f);
    lo = f2h((f - h2f(hi)) * SPLIT_SCALE);
}

// 32x32x16 fragment layout: lane l holds [row/col = l&31][k = kt*16 + (l>>5)*8 + 0..7]
__device__ __forceinline__ size_t aoff(int lvl, int mt, int kt, int lane) {
    return ((size_t)((lvl * 8 + mt) * KT16 + kt) * 64 + lane) * 8;
}
__device__ __forceinline__ size_t boff(int lvl, int ct, int kt, int lane) {
    return ((size_t)((lvl * 128 + ct) * KT16 + kt) * 64 + lane) * 8;
}

__device__ __forceinline__ void write_frag8(unsigned short* __restrict__ Af, int n, int k8, const float* v) {
    int mt = n >> 5, kt = k8 >> 4;
    int lane = (n & 31) + 32 * ((k8 >> 3) & 1);
    unsigned short s[8][2];
#pragma unroll
    for (int i = 0; i < 8; ++i) split2(v[i], s[i][0], s[i][1]);
#pragma unroll
    for (int lvl = 0; lvl < 2; ++lvl) {
        uint4 p;
        p.x = (unsigned)s[0][lvl] | ((unsigned)s[1][lvl] << 16);
        p.y = (unsigned)s[2][lvl] | ((unsigned)s[3][lvl] << 16);
        p.z = (unsigned)s[4][lvl] | ((unsigned)s[5][lvl] << 16);
        p.w = (unsigned)s[6][lvl] | ((unsigned)s[7][lvl] << 16);
        *reinterpret_cast<uint4*>(Af + aoff(lvl, mt, kt, lane)) = p;
    }
}

// ---------------- weight split: W[k][j] f32 -> B-fragment order (2-level f16) ----------------
__global__ __launch_bounds__(256) void wsplit_kernel(const float* __restrict__ Wx,
                                                     const float* __restrict__ Wh,
                                                     const float* __restrict__ Wattn,
                                                     unsigned short* __restrict__ Bf) {
    __shared__ float tile[32][33];
    int k0 = blockIdx.x * 32, j0 = blockIdx.y * 32;
    int t = threadIdx.x;
    int rl = t >> 3, c4 = (t & 7) * 4;
    int seg = k0 >> 10;
    const float* W = (seg == 0) ? Wx : (seg == 1) ? Wh : Wattn;
    const float4 v = *reinterpret_cast<const float4*>(W + (size_t)((k0 & 1023) + rl) * FOURH + j0 + c4);
    tile[rl][c4 + 0] = v.x; tile[rl][c4 + 1] = v.y; tile[rl][c4 + 2] = v.z; tile[rl][c4 + 3] = v.w;
    __syncthreads();
    int jl = t >> 3, k4 = (t & 7) * 4;
    unsigned short s[4][2];
#pragma unroll
    for (int i = 0; i < 4; ++i) split2(tile[k4 + i][jl], s[i][0], s[i][1]);
    int j = j0 + jl;
    int kg = k0 + k4;
    int ct = j >> 5, kt = kg >> 4;
    int lane = (j & 31) + 32 * ((kg >> 3) & 1);
    int sub = kg & 7;   // 0 or 4
#pragma unroll
    for (int lvl = 0; lvl < 2; ++lvl) {
        uint2 p;
        p.x = (unsigned)s[0][lvl] | ((unsigned)s[1][lvl] << 16);
        p.y = (unsigned)s[2][lvl] | ((unsigned)s[3][lvl] << 16);
        *reinterpret_cast<uint2*>(Bf + boff(lvl, ct, kt, lane) + sub) = p;
    }
}

// ---------------- shared device phases (512 threads) ----------------
__device__ __forceinline__ void attn_phase(const float* __restrict__ A, int n, int tid,
                                           const float* hsh, float* ash, float* red2) {
    int lane = tid & 63, wave = tid >> 6;   // 8 waves
    const float* An = A + (size_t)n * HH * 16;
    float areg[2][16];
    float part[16];
#pragma unroll
    for (int k = 0; k < 16; ++k) part[k] = 0.f;
#pragma unroll
    for (int i = 0; i < 2; ++i) {
        int hh = tid + i * 512;
        float hv = hsh[hh];
        const float* ap = An + (size_t)hh * 16;
#pragma unroll
        for (int k = 0; k < 16; ++k) {
            float av = ap[k];
            areg[i][k] = av;
            part[k] += hv * av;
        }
    }
#pragma unroll
    for (int k = 0; k < 16; ++k) {
        float v = part[k];
#pragma unroll
        for (int off = 32; off > 0; off >>= 1) v += __shfl_down(v, off);
        if (lane == 0) red2[wave * 16 + k] = v;
    }
    __syncthreads();
    float w[16];
    float mx = -1e30f;
#pragma unroll
    for (int k = 0; k < 16; ++k) {
        float s = 0.f;
#pragma unroll
        for (int q = 0; q < 8; ++q) s += red2[q * 16 + k];
        s *= 0.03125f;
        w[k] = s;
        mx = fmaxf(mx, s);
    }
    float sum = 0.f;
#pragma unroll
    for (int k = 0; k < 16; ++k) {
        w[k] = expf(w[k] - mx);
        sum += w[k];
    }
    float inv = 1.0f / sum;
#pragma unroll
    for (int k = 0; k < 16; ++k) w[k] *= inv;
#pragma unroll
    for (int i = 0; i < 2; ++i) {
        float s = 0.f;
#pragma unroll
        for (int k = 0; k < 16; ++k) s += areg[i][k] * w[k];
        ash[tid + i * 512] = s;
    }
}

// 3-way-parallel frag writes: seg 0 -> h, seg 1 -> attn, seg 2 -> x_{tnext}
__device__ __forceinline__ void write_state_frags(unsigned short* __restrict__ Af,
                                                  const float* __restrict__ x,
                                                  const float* hsh, const float* ash,
                                                  int n, int tnext, int tid) {
    int seg = tid >> 7;          // 0..3
    int k8 = (tid & 127) * 8;
    float v[8];
    if (seg == 0) {
#pragma unroll
        for (int i = 0; i < 8; ++i) v[i] = hsh[k8 + i];
        write_frag8(Af, n, 1024 + k8, v);
    } else if (seg == 1) {
#pragma unroll
        for (int i = 0; i < 8; ++i) v[i] = ash[k8 + i];
        write_frag8(Af, n, 2048 + k8, v);
    } else if (seg == 2 && tnext < TT) {
        const float4* xp = reinterpret_cast<const float4*>(x + ((size_t)n * TT + tnext) * DD + k8);
        float4 x0 = xp[0], x1 = xp[1];
        v[0] = x0.x; v[1] = x0.y; v[2] = x0.z; v[3] = x0.w;
        v[4] = x1.x; v[5] = x1.y; v[6] = x1.z; v[7] = x1.w;
        write_frag8(Af, n, k8, v);
    }
}

// ---------------- init ----------------
__global__ __launch_bounds__(512) void initk(const float* __restrict__ A,
                                             const float* __restrict__ x,
                                             float* __restrict__ c,
                                             unsigned short* __restrict__ Af) {
    int n = blockIdx.x, tid = threadIdx.x;
    __shared__ float hsh[HH], ash[HH];
    __shared__ float red2[128];
#pragma unroll
    for (int i = 0; i < 2; ++i) {
        int hh = tid + i * 512;
        const float* ap = A + ((size_t)n * HH + hh) * 16;
        float s = 0.f;
#pragma unroll
        for (int k = 0; k < 16; ++k) s += ap[k];
        s *= (1.0f / 16.0f);
        c[(size_t)n * HH + hh] = s;
        hsh[hh] = s;
    }
    __syncthreads();
    attn_phase(A, n, tid, hsh, ash, red2);
    __syncthreads();
    write_state_frags(Af, x, hsh, ash, n, 0, tid);
}

// ---------------- MFMA GEMM: A global->VGPR direct (chunk-parity dbuf), B-only LDS ----
// grid 256 = 64 colb x 4 z; 512 thr = 8 waves (4 wm x 2 wn); M=256, N=64, K=768 per block
// chunk = 2 kt. B: 8 frags of 1KB per chunk in LDS (wave w stages frag w; 1 load/thread).
// A: 8 uint4/thread/chunk loaded straight to VGPRs (2mt x 2lvl x 2ktc), dbuf by parity.
// Per chunk/thread issues: 8 A-loads (c+1) + 1 B-stage (c+2) = 9 -> top-of-chunk vmcnt(9).
#define KTPB 48
#define NCHUNK 24                 // KTPB / 2
#define BUFS 4096                 // 8 frags * 512 shorts = 8 KB per buffer

#define STAGE_B(bidx, cc)                                                                      \
    {                                                                                          \
        __builtin_amdgcn_global_load_lds(                                                      \
            (const __attribute__((address_space(1))) unsigned int*)(sbB + (size_t)(cc) * 1024),\
            (__attribute__((address_space(3))) unsigned int*)&Bsm[(bidx)][ldsB],               \
            16, 0, 0);                                                                         \
    }

// q = ktc*4 + lvl*2 + mi
#define LOADA(dst, cc)                                                                         \
    {                                                                                          \
        _Pragma("unroll") for (int q = 0; q < 8; ++q) {                                        \
            int ktc_ = q >> 2, lvl_ = (q >> 1) & 1, mi_ = q & 1;                               \
            dst[q] = *reinterpret_cast<const uint4*>(pa[lvl_][mi_] + (size_t)((cc) * 2 + ktc_) * 512); \
        }                                                                                      \
    }

#define CHUNK(Acur, Anext, cc, buf)                                                            \
    {                                                                                          \
        if ((cc) == NCHUNK - 1) { asm volatile("s_waitcnt vmcnt(0)" ::: "memory"); }           \
        else                    { asm volatile("s_waitcnt vmcnt(9)" ::: "memory"); }           \
        __builtin_amdgcn_sched_barrier(0);                                                     \
        __builtin_amdgcn_s_barrier();                                                          \
        __builtin_amdgcn_sched_barrier(0);                                                     \
        if ((cc) + 1 < NCHUNK) LOADA(Anext, (cc) + 1)                                          \
        __builtin_amdgcn_sched_barrier(0);                                                     \
        __builtin_amdgcn_s_setprio(1);                                                         \
        _Pragma("unroll") for (int ktc = 0; ktc < 2; ++ktc) {                                  \
            const unsigned short* bp = &Bsm[buf][(ktc * 4 + wn) * 512 + l * 8];                \
            f16x8 b0 = *reinterpret_cast<const f16x8*>(bp);                                    \
            f16x8 b1 = *reinterpret_cast<const f16x8*>(bp + 1024);                             \
            _Pragma("unroll") for (int mi = 0; mi < 2; ++mi) {                                 \
                f16x8 aH = __builtin_bit_cast(f16x8, Acur[ktc * 4 + mi]);                      \
                f16x8 aL = __builtin_bit_cast(f16x8, Acur[ktc * 4 + 2 + mi]);                  \
                accH[mi] = __builtin_amdgcn_mfma_f32_32x32x16_f16(aH, b0, accH[mi], 0, 0, 0);  \
                accM[mi] = __builtin_amdgcn_mfma_f32_32x32x16_f16(aH, b1, accM[mi], 0, 0, 0);  \
                accM[mi] = __builtin_amdgcn_mfma_f32_32x32x16_f16(aL, b0, accM[mi], 0, 0, 0);  \
            }                                                                                  \
        }                                                                                      \
        __builtin_amdgcn_s_setprio(0);                                                         \
        __builtin_amdgcn_sched_barrier(0);                                                     \
        __builtin_amdgcn_s_barrier();                                                          \
        __builtin_amdgcn_sched_barrier(0);                                                     \
        if ((cc) + 2 < NCHUNK) STAGE_B((buf), (cc) + 2)                                        \
    }

__global__ __launch_bounds__(512) void gemm_mfma(const unsigned short* __restrict__ Af,
                                                 const unsigned short* __restrict__ Bf,
                                                 float* __restrict__ apart) {
    __shared__ __align__(16) unsigned short Bsm[2][BUFS];   // 2 x 8 KB
    int tid = threadIdx.x;
    int l = tid & 63, w = tid >> 6;       // 8 waves: 4 wm x 2 wn
    int wm = w & 3, wn = w >> 2;
    int bid = blockIdx.x;
    int id = ((bid & 7) << 5) + (bid >> 3);   // XCD-chunked bijective swizzle (256 % 8 == 0)
    int colb = id & 63, z = id >> 6;
    int kt0 = z * KTPB;

    // B staging: wave w stages frag g = w: ct = g&1, lvl = (g>>1)&1, ktc = g>>2
    const unsigned short* sbB = Bf + boff((w >> 1) & 1, colb * 2 + (w & 1), kt0 + (w >> 2), l);
    int ldsB = w * 512;

    // A fragment base pointers (advance by kt*512 elems)
    const unsigned short* pa[2][2];
#pragma unroll
    for (int lvl = 0; lvl < 2; ++lvl)
#pragma unroll
        for (int mi = 0; mi < 2; ++mi)
            pa[lvl][mi] = Af + aoff(lvl, wm * 2 + mi, kt0, l);

    f32x16 accH[2] = {};
    f32x16 accM[2] = {};
    uint4 A0[8], A1[8];

    STAGE_B(0, 0)
    STAGE_B(1, 1)
    LOADA(A0, 0)

    for (int cc = 0; cc < NCHUNK; cc += 2) {
        CHUNK(A0, A1, cc, 0)
        CHUNK(A1, A0, cc + 1, 1)
    }

    // epilogue: combine hi + mid/2048; C/D layout: col=l&31, row=(r&3)+8*(r>>2)+4*(l>>5)
    float* plane = apart + (size_t)z * P1;
    int col = colb * 64 + wn * 32 + (l & 31);
#pragma unroll
    for (int mi = 0; mi < 2; ++mi) {
        int rbase = (wm * 2 + mi) * 32 + (l >> 5) * 4;
#pragma unroll
        for (int r = 0; r < 16; ++r) {
            int row = rbase + (r & 3) + 8 * (r >> 2);
            plane[(size_t)row * FOURH + col] = accH[mi][r] + accM[mi][r] * INV_SPLIT;
        }
    }
}

// ---------------- pointwise: gates + LSTM + attn + frag writes (512 thr, float2-vectorized) ----------------
__global__ __launch_bounds__(512) void pointwise(const float* __restrict__ apart,
                                                 const float* __restrict__ bias,
                                                 const float* __restrict__ A,
                                                 const float* __restrict__ x,
                                                 float* __restrict__ c,
                                                 float* __restrict__ out,
                                                 unsigned short* __restrict__ Af, int t) {
    int n = blockIdx.x, tid = threadIdx.x;
    __shared__ float hsh[HH], ash[HH];
    __shared__ float red2[128];
    const float* ap = apart + (size_t)n * FOURH;
    int hh2 = tid * 2;
    float2 g2[4];
#pragma unroll
    for (int g = 0; g < 4; ++g) {
        int j = g * 1024 + hh2;
        float2 s = *reinterpret_cast<const float2*>(bias + j);
#pragma unroll
        for (int zz = 0; zz < NZ; ++zz) {
            float2 p = *reinterpret_cast<const float2*>(ap + (size_t)zz * P1 + j);
            s.x += p.x; s.y += p.y;
        }
        g2[g] = s;
    }
    float2 cold = *reinterpret_cast<const float2*>(c + (size_t)n * HH + hh2);
    float2 hn2;
    {
        float ig = 1.f / (1.f + expf(-g2[0].x));
        float fg = 1.f / (1.f + expf(-g2[1].x));
        float og = 1.f / (1.f + expf(-g2[2].x));
        float gg = tanhf(g2[3].x);
        float cn = fg * cold.x + ig * gg;
        hn2.x = og * tanhf(cn);
        cold.x = cn;
    }
    {
        float ig = 1.f / (1.f + expf(-g2[0].y));
        float fg = 1.f / (1.f + expf(-g2[1].y));
        float og = 1.f / (1.f + expf(-g2[2].y));
        float gg = tanhf(g2[3].y);
        float cn = fg * cold.y + ig * gg;
        hn2.y = og * tanhf(cn);
        cold.y = cn;
    }
    *reinterpret_cast<float2*>(c + (size_t)n * HH + hh2) = cold;
    *reinterpret_cast<float2*>(out + ((size_t)n * TT + t) * HH + hh2) = hn2;
    *reinterpret_cast<float2*>(&hsh[hh2]) = hn2;
    __syncthreads();
    attn_phase(A, n, tid, hsh, ash, red2);
    __syncthreads();
    write_state_frags(Af, x, hsh, ash, n, t + 1, tid);
}

extern "C" void kernel_launch(void* const* d_in, const int* in_sizes, int n_in,
                              void* d_out, int out_size, void* d_ws, size_t ws_size,
                              hipStream_t stream) {
    const float* x     = (const float*)d_in[0];
    const float* A     = (const float*)d_in[1];
    const float* Wx    = (const float*)d_in[2];
    const float* Wh    = (const float*)d_in[3];
    const float* Wattn = (const float*)d_in[4];
    const float* b     = (const float*)d_in[5];
    float* out = (float*)d_out;

    unsigned short* Bf = (unsigned short*)d_ws;        // 2*BF_LVL f16 = 50.3 MB
    unsigned short* Af = Bf + 2 * BF_LVL;              // 2*AF_LVL f16 = 3.1 MB
    float* apart = (float*)(Af + 2 * AF_LVL);          // 4 * P1 f32 = 16 MB
    float* c = apart + (size_t)NZ * P1;                // 1 MB

    wsplit_kernel<<<dim3(KTOT / 32, FOURH / 32), 256, 0, stream>>>(Wx, Wh, Wattn, Bf);
    initk<<<NB, 512, 0, stream>>>(A, x, c, Af);

    for (int t = 0; t < TT; ++t) {
        gemm_mfma<<<256, 512, 0, stream>>>(Af, Bf, apart);
        pointwise<<<NB, 512, 0, stream>>>(apart, b, A, x, c, out, Af, t);
    }
}

// Round 16
// 2613.692 us; speedup vs baseline: 1.1528x; 1.1528x over previous
//
#include <hip/hip_runtime.h>
#include <math.h>

#define NB 256
#define TT 64
#define DD 1024
#define HH 1024
#define FOURH 4096
#define KTOT 3072
#define KT16 192                  // K-tiles of 16
#define P1 (NB * FOURH)           // one partial plane (f32 elems)
#define NZ 4

#define AF_LVL 786432ull          // 8 mt * 192 kt * 512
#define BF_LVL 12582912ull        // 128 ct * 192 kt * 512
#define SPLIT_SCALE 2048.0f
#define INV_SPLIT (1.0f / 2048.0f)

typedef _Float16 f16x8 __attribute__((ext_vector_type(8)));
typedef float f32x16 __attribute__((ext_vector_type(16)));
typedef float f32x2v __attribute__((ext_vector_type(2)));
typedef float f32x4v __attribute__((ext_vector_type(4)));

__device__ __forceinline__ unsigned short f2h(float f) {
    _Float16 h = (_Float16)f;
    unsigned short u;
    __builtin_memcpy(&u, &h, 2);
    return u;
}
__device__ __forceinline__ float h2f(unsigned short u) {
    _Float16 h;
    __builtin_memcpy(&h, &u, 2);
    return (float)h;
}
// 2-way fp16 split; lo pre-scaled by 2^11 to stay out of subnormal range
__device__ __forceinline__ void split2(float f, unsigned short& hi, unsigned short& lo) {
    hi = f2h(f);
    lo = f2h((f - h2f(hi)) * SPLIT_SCALE);
}

// 32x32x16 fragment layout: lane l holds [row/col = l&31][k = kt*16 + (l>>5)*8 + 0..7]
__device__ __forceinline__ size_t aoff(int lvl, int mt, int kt, int lane) {
    return ((size_t)((lvl * 8 + mt) * KT16 + kt) * 64 + lane) * 8;
}
__device__ __forceinline__ size_t boff(int lvl, int ct, int kt, int lane) {
    return ((size_t)((lvl * 128 + ct) * KT16 + kt) * 64 + lane) * 8;
}

__device__ __forceinline__ void write_frag8(unsigned short* __restrict__ Af, int n, int k8, const float* v) {
    int mt = n >> 5, kt = k8 >> 4;
    int lane = (n & 31) + 32 * ((k8 >> 3) & 1);
    unsigned short s[8][2];
#pragma unroll
    for (int i = 0; i < 8; ++i) split2(v[i], s[i][0], s[i][1]);
#pragma unroll
    for (int lvl = 0; lvl < 2; ++lvl) {
        uint4 p;
        p.x = (unsigned)s[0][lvl] | ((unsigned)s[1][lvl] << 16);
        p.y = (unsigned)s[2][lvl] | ((unsigned)s[3][lvl] << 16);
        p.z = (unsigned)s[4][lvl] | ((unsigned)s[5][lvl] << 16);
        p.w = (unsigned)s[6][lvl] | ((unsigned)s[7][lvl] << 16);
        *reinterpret_cast<uint4*>(Af + aoff(lvl, mt, kt, lane)) = p;
    }
}

// ---------------- weight split: W[k][j] f32 -> B-fragment order (2-level f16) ----------------
__global__ __launch_bounds__(256) void wsplit_kernel(const float* __restrict__ Wx,
                                                     const float* __restrict__ Wh,
                                                     const float* __restrict__ Wattn,
                                                     unsigned short* __restrict__ Bf) {
    __shared__ float tile[32][33];
    int k0 = blockIdx.x * 32, j0 = blockIdx.y * 32;
    int t = threadIdx.x;
    int rl = t >> 3, c4 = (t & 7) * 4;
    int seg = k0 >> 10;
    const float* W = (seg == 0) ? Wx : (seg == 1) ? Wh : Wattn;
    const float4 v = *reinterpret_cast<const float4*>(W + (size_t)((k0 & 1023) + rl) * FOURH + j0 + c4);
    tile[rl][c4 + 0] = v.x; tile[rl][c4 + 1] = v.y; tile[rl][c4 + 2] = v.z; tile[rl][c4 + 3] = v.w;
    __syncthreads();
    int jl = t >> 3, k4 = (t & 7) * 4;
    unsigned short s[4][2];
#pragma unroll
    for (int i = 0; i < 4; ++i) split2(tile[k4 + i][jl], s[i][0], s[i][1]);
    int j = j0 + jl;
    int kg = k0 + k4;
    int ct = j >> 5, kt = kg >> 4;
    int lane = (j & 31) + 32 * ((kg >> 3) & 1);
    int sub = kg & 7;   // 0 or 4
#pragma unroll
    for (int lvl = 0; lvl < 2; ++lvl) {
        uint2 p;
        p.x = (unsigned)s[0][lvl] | ((unsigned)s[1][lvl] << 16);
        p.y = (unsigned)s[2][lvl] | ((unsigned)s[3][lvl] << 16);
        *reinterpret_cast<uint2*>(Bf + boff(lvl, ct, kt, lane) + sub) = p;
    }
}

// ---------------- shared device phases (512 threads) ----------------
__device__ __forceinline__ void attn_phase(const float* __restrict__ A, int n, int tid,
                                           const float* hsh, float* ash, float* red2) {
    int lane = tid & 63, wave = tid >> 6;   // 8 waves
    const float* An = A + (size_t)n * HH * 16;
    float areg[2][16];
    float part[16];
#pragma unroll
    for (int k = 0; k < 16; ++k) part[k] = 0.f;
#pragma unroll
    for (int i = 0; i < 2; ++i) {
        int hh = tid + i * 512;
        float hv = hsh[hh];
        const float* ap = An + (size_t)hh * 16;
#pragma unroll
        for (int k = 0; k < 16; ++k) {
            float av = ap[k];
            areg[i][k] = av;
            part[k] += hv * av;
        }
    }
#pragma unroll
    for (int k = 0; k < 16; ++k) {
        float v = part[k];
#pragma unroll
        for (int off = 32; off > 0; off >>= 1) v += __shfl_down(v, off);
        if (lane == 0) red2[wave * 16 + k] = v;
    }
    __syncthreads();
    float w[16];
    float mx = -1e30f;
#pragma unroll
    for (int k = 0; k < 16; ++k) {
        float s = 0.f;
#pragma unroll
        for (int q = 0; q < 8; ++q) s += red2[q * 16 + k];
        s *= 0.03125f;
        w[k] = s;
        mx = fmaxf(mx, s);
    }
    float sum = 0.f;
#pragma unroll
    for (int k = 0; k < 16; ++k) {
        w[k] = expf(w[k] - mx);
        sum += w[k];
    }
    float inv = 1.0f / sum;
#pragma unroll
    for (int k = 0; k < 16; ++k) w[k] *= inv;
#pragma unroll
    for (int i = 0; i < 2; ++i) {
        float s = 0.f;
#pragma unroll
        for (int k = 0; k < 16; ++k) s += areg[i][k] * w[k];
        ash[tid + i * 512] = s;
    }
}

// 3-way-parallel frag writes: seg 0 -> h, seg 1 -> attn, seg 2 -> x_{tnext}
__device__ __forceinline__ void write_state_frags(unsigned short* __restrict__ Af,
                                                  const float* __restrict__ x,
                                                  const float* hsh, const float* ash,
                                                  int n, int tnext, int tid) {
    int seg = tid >> 7;          // 0..3
    int k8 = (tid & 127) * 8;
    float v[8];
    if (seg == 0) {
#pragma unroll
        for (int i = 0; i < 8; ++i) v[i] = hsh[k8 + i];
        write_frag8(Af, n, 1024 + k8, v);
    } else if (seg == 1) {
#pragma unroll
        for (int i = 0; i < 8; ++i) v[i] = ash[k8 + i];
        write_frag8(Af, n, 2048 + k8, v);
    } else if (seg == 2 && tnext < TT) {
        const f32x4v* xp = reinterpret_cast<const f32x4v*>(x + ((size_t)n * TT + tnext) * DD + k8);
        f32x4v x0 = __builtin_nontemporal_load(xp);
        f32x4v x1 = __builtin_nontemporal_load(xp + 1);
        v[0] = x0[0]; v[1] = x0[1]; v[2] = x0[2]; v[3] = x0[3];
        v[4] = x1[0]; v[5] = x1[1]; v[6] = x1[2]; v[7] = x1[3];
        write_frag8(Af, n, k8, v);
    }
}

// ---------------- init ----------------
__global__ __launch_bounds__(512) void initk(const float* __restrict__ A,
                                             const float* __restrict__ x,
                                             float* __restrict__ c,
                                             unsigned short* __restrict__ Af) {
    int n = blockIdx.x, tid = threadIdx.x;
    __shared__ float hsh[HH], ash[HH];
    __shared__ float red2[128];
#pragma unroll
    for (int i = 0; i < 2; ++i) {
        int hh = tid + i * 512;
        const float* ap = A + ((size_t)n * HH + hh) * 16;
        float s = 0.f;
#pragma unroll
        for (int k = 0; k < 16; ++k) s += ap[k];
        s *= (1.0f / 16.0f);
        c[(size_t)n * HH + hh] = s;
        hsh[hh] = s;
    }
    __syncthreads();
    attn_phase(A, n, tid, hsh, ash, red2);
    __syncthreads();
    write_state_frags(Af, x, hsh, ash, n, 0, tid);
}

// ---------------- MFMA GEMM: A+B staged via global_load_lds, counted-vmcnt 2-phase pipeline ----
// (R8 structure verbatim; only the apart epilogue stores are nontemporal now)
#define KTPB 48
#define NCHUNK 24                 // KTPB / 2
#define BUFS 20480                // 40 * 512 shorts = 40 KB per buffer

#define STAGE(cc)                                                                              \
    {                                                                                          \
        _Pragma("unroll") for (int j = 0; j < 5; ++j) {                                        \
            __builtin_amdgcn_global_load_lds(                                                  \
                (const __attribute__((address_space(1))) unsigned int*)(sb[j] + (size_t)(cc) * 1024), \
                (__attribute__((address_space(3))) unsigned int*)&Bsm[(cc) & 1][ldsoff[j]],    \
                16, 0, 0);                                                                     \
        }                                                                                      \
    }

__global__ __launch_bounds__(512) void gemm_mfma(const unsigned short* __restrict__ Af,
                                                 const unsigned short* __restrict__ Bf,
                                                 float* __restrict__ apart) {
    __shared__ __align__(16) unsigned short Bsm[2][BUFS];   // 2 x 40 KB
    int tid = threadIdx.x;
    int l = tid & 63, w = tid >> 6;       // 8 waves: 4 wm x 2 wn
    int wm = w & 3, wn = w >> 2;
    int bid = blockIdx.x;
    int id = ((bid & 7) << 5) + (bid >> 3);   // XCD-chunked bijective swizzle (256 % 8 == 0)
    int colb = id & 63, z = id >> 6;
    int kt0 = z * KTPB;

    // staging assignment: thread handles frag ids f = w + 8j (wave-uniform), lane = l
    const unsigned short* sb[5];
    int ldsoff[5];
#pragma unroll
    for (int j = 0; j < 5; ++j) {
        int f = w + 8 * j;
        if (f < 32) {
            int ktc = f >> 4, lvl = (f >> 3) & 1, mt = f & 7;
            sb[j] = Af + aoff(lvl, mt, kt0 + ktc, l);
        } else {
            int g = f - 32;
            int ktc = g >> 2, lvl = (g >> 1) & 1, ct = g & 1;
            sb[j] = Bf + boff(lvl, colb * 2 + ct, kt0 + ktc, l);
        }
        ldsoff[j] = f * 512;
    }

    f32x16 accH[2] = {};
    f32x16 accM[2] = {};

    STAGE(0)
    STAGE(1)

    for (int cc = 0; cc < NCHUNK; ++cc) {
        if (cc + 1 < NCHUNK) {
            asm volatile("s_waitcnt vmcnt(5)" ::: "memory");   // chunk cc landed; cc+1 in flight
        } else {
            asm volatile("s_waitcnt vmcnt(0)" ::: "memory");
        }
        __builtin_amdgcn_sched_barrier(0);
        __builtin_amdgcn_s_barrier();      // all threads' chunk-cc stages visible

        const unsigned short* base = &Bsm[cc & 1][0];
#pragma unroll
        for (int ktc = 0; ktc < 2; ++ktc) {
            const unsigned short* bp = base + (size_t)(32 + ktc * 4 + wn) * 512 + l * 8;   // lvl stride 2*512
            f16x8 b0 = *reinterpret_cast<const f16x8*>(bp);
            f16x8 b1 = *reinterpret_cast<const f16x8*>(bp + 1024);
            const unsigned short* ap0 = base + (size_t)(ktc * 16 + wm * 2) * 512 + l * 8;
            f16x8 a0m0 = *reinterpret_cast<const f16x8*>(ap0);
            f16x8 a0m1 = *reinterpret_cast<const f16x8*>(ap0 + 512);
            f16x8 a1m0 = *reinterpret_cast<const f16x8*>(ap0 + 8 * 512);
            f16x8 a1m1 = *reinterpret_cast<const f16x8*>(ap0 + 9 * 512);
            accH[0] = __builtin_amdgcn_mfma_f32_32x32x16_f16(a0m0, b0, accH[0], 0, 0, 0);
            accM[0] = __builtin_amdgcn_mfma_f32_32x32x16_f16(a0m0, b1, accM[0], 0, 0, 0);
            accM[0] = __builtin_amdgcn_mfma_f32_32x32x16_f16(a1m0, b0, accM[0], 0, 0, 0);
            accH[1] = __builtin_amdgcn_mfma_f32_32x32x16_f16(a0m1, b0, accH[1], 0, 0, 0);
            accM[1] = __builtin_amdgcn_mfma_f32_32x32x16_f16(a0m1, b1, accM[1], 0, 0, 0);
            accM[1] = __builtin_amdgcn_mfma_f32_32x32x16_f16(a1m1, b0, accM[1], 0, 0, 0);
        }

        __builtin_amdgcn_sched_barrier(0);
        __builtin_amdgcn_s_barrier();      // buffer (cc&1) free for overwrite
        if (cc + 2 < NCHUNK) STAGE(cc + 2)   // lands during chunk cc+1's compute
    }

    // epilogue: combine hi + mid/2048; nontemporal stores keep apart out of L3
    float* plane = apart + (size_t)z * P1;
    int col = colb * 64 + wn * 32 + (l & 31);
#pragma unroll
    for (int mi = 0; mi < 2; ++mi) {
        int rbase = (wm * 2 + mi) * 32 + (l >> 5) * 4;
#pragma unroll
        for (int r = 0; r < 16; ++r) {
            int row = rbase + (r & 3) + 8 * (r >> 2);
            __builtin_nontemporal_store(accH[mi][r] + accM[mi][r] * INV_SPLIT,
                                        &plane[(size_t)row * FOURH + col]);
        }
    }
}

// ---------------- pointwise: gates + LSTM + attn + frag writes (512 thr, nt loads/stores) ----------------
__global__ __launch_bounds__(512) void pointwise(const float* __restrict__ apart,
                                                 const float* __restrict__ bias,
                                                 const float* __restrict__ A,
                                                 const float* __restrict__ x,
                                                 float* __restrict__ c,
                                                 float* __restrict__ out,
                                                 unsigned short* __restrict__ Af, int t) {
    int n = blockIdx.x, tid = threadIdx.x;
    __shared__ float hsh[HH], ash[HH];
    __shared__ float red2[128];
    const float* ap = apart + (size_t)n * FOURH;
    int hh2 = tid * 2;
    f32x2v g2[4];
#pragma unroll
    for (int g = 0; g < 4; ++g) {
        int j = g * 1024 + hh2;
        f32x2v s = *reinterpret_cast<const f32x2v*>(bias + j);
#pragma unroll
        for (int zz = 0; zz < NZ; ++zz) {
            f32x2v p = __builtin_nontemporal_load(
                reinterpret_cast<const f32x2v*>(ap + (size_t)zz * P1 + j));
            s[0] += p[0]; s[1] += p[1];
        }
        g2[g] = s;
    }
    f32x2v cold = *reinterpret_cast<const f32x2v*>(c + (size_t)n * HH + hh2);
    f32x2v hn2;
    {
        float ig = 1.f / (1.f + expf(-g2[0][0]));
        float fg = 1.f / (1.f + expf(-g2[1][0]));
        float og = 1.f / (1.f + expf(-g2[2][0]));
        float gg = tanhf(g2[3][0]);
        float cn = fg * cold[0] + ig * gg;
        hn2[0] = og * tanhf(cn);
        cold[0] = cn;
    }
    {
        float ig = 1.f / (1.f + expf(-g2[0][1]));
        float fg = 1.f / (1.f + expf(-g2[1][1]));
        float og = 1.f / (1.f + expf(-g2[2][1]));
        float gg = tanhf(g2[3][1]);
        float cn = fg * cold[1] + ig * gg;
        hn2[1] = og * tanhf(cn);
        cold[1] = cn;
    }
    *reinterpret_cast<f32x2v*>(c + (size_t)n * HH + hh2) = cold;
    __builtin_nontemporal_store(hn2, reinterpret_cast<f32x2v*>(out + ((size_t)n * TT + t) * HH + hh2));
    *reinterpret_cast<f32x2v*>(&hsh[hh2]) = hn2;
    __syncthreads();
    attn_phase(A, n, tid, hsh, ash, red2);
    __syncthreads();
    write_state_frags(Af, x, hsh, ash, n, t + 1, tid);
}

extern "C" void kernel_launch(void* const* d_in, const int* in_sizes, int n_in,
                              void* d_out, int out_size, void* d_ws, size_t ws_size,
                              hipStream_t stream) {
    const float* x     = (const float*)d_in[0];
    const float* A     = (const float*)d_in[1];
    const float* Wx    = (const float*)d_in[2];
    const float* Wh    = (const float*)d_in[3];
    const float* Wattn = (const float*)d_in[4];
    const float* b     = (const float*)d_in[5];
    float* out = (float*)d_out;

    unsigned short* Bf = (unsigned short*)d_ws;        // 2*BF_LVL f16 = 50.3 MB
    unsigned short* Af = Bf + 2 * BF_LVL;              // 2*AF_LVL f16 = 3.1 MB
    float* apart = (float*)(Af + 2 * AF_LVL);          // 4 * P1 f32 = 16 MB
    float* c = apart + (size_t)NZ * P1;                // 1 MB

    wsplit_kernel<<<dim3(KTOT / 32, FOURH / 32), 256, 0, stream>>>(Wx, Wh, Wattn, Bf);
    initk<<<NB, 512, 0, stream>>>(A, x, c, Af);

    for (int t = 0; t < TT; ++t) {
        gemm_mfma<<<256, 512, 0, stream>>>(Af, Bf, apart);
        pointwise<<<NB, 512, 0, stream>>>(apart, b, A, x, c, out, Af, t);
    }
}

// Round 17
// 2607.461 us; speedup vs baseline: 1.1556x; 1.0024x over previous
//
#include <hip/hip_runtime.h>
#include <math.h>

#define NB 256
#define TT 64
#define DD 1024
#define HH 1024
#define FOURH 4096
#define KTOT 3072
#define KT16 192                  // K-tiles of 16
#define P1 (NB * FOURH)           // one partial plane (f32 elems)
#define NZ 4

#define AF_LVL 786432ull          // 8 mt * 192 kt * 512
#define BF_LVL 12582912ull        // 128 ct * 192 kt * 512
#define SPLIT_SCALE 2048.0f
#define INV_SPLIT (1.0f / 2048.0f)

typedef _Float16 f16x8 __attribute__((ext_vector_type(8)));
typedef float f32x16 __attribute__((ext_vector_type(16)));
typedef float f32x2v __attribute__((ext_vector_type(2)));
typedef float f32x4v __attribute__((ext_vector_type(4)));

__device__ __forceinline__ unsigned short f2h(float f) {
    _Float16 h = (_Float16)f;
    unsigned short u;
    __builtin_memcpy(&u, &h, 2);
    return u;
}
__device__ __forceinline__ float h2f(unsigned short u) {
    _Float16 h;
    __builtin_memcpy(&h, &u, 2);
    return (float)h;
}
// 2-way fp16 split; lo pre-scaled by 2^11 to stay out of subnormal range
__device__ __forceinline__ void split2(float f, unsigned short& hi, unsigned short& lo) {
    hi = f2h(f);
    lo = f2h((f - h2f(hi)) * SPLIT_SCALE);
}

// 32x32x16 fragment layout: lane l holds [row/col = l&31][k = kt*16 + (l>>5)*8 + 0..7]
__device__ __forceinline__ size_t aoff(int lvl, int mt, int kt, int lane) {
    return ((size_t)((lvl * 8 + mt) * KT16 + kt) * 64 + lane) * 8;
}
__device__ __forceinline__ size_t boff(int lvl, int ct, int kt, int lane) {
    return ((size_t)((lvl * 128 + ct) * KT16 + kt) * 64 + lane) * 8;
}

__device__ __forceinline__ void write_frag8(unsigned short* __restrict__ Af, int n, int k8, const float* v) {
    int mt = n >> 5, kt = k8 >> 4;
    int lane = (n & 31) + 32 * ((k8 >> 3) & 1);
    unsigned short s[8][2];
#pragma unroll
    for (int i = 0; i < 8; ++i) split2(v[i], s[i][0], s[i][1]);
#pragma unroll
    for (int lvl = 0; lvl < 2; ++lvl) {
        uint4 p;
        p.x = (unsigned)s[0][lvl] | ((unsigned)s[1][lvl] << 16);
        p.y = (unsigned)s[2][lvl] | ((unsigned)s[3][lvl] << 16);
        p.z = (unsigned)s[4][lvl] | ((unsigned)s[5][lvl] << 16);
        p.w = (unsigned)s[6][lvl] | ((unsigned)s[7][lvl] << 16);
        *reinterpret_cast<uint4*>(Af + aoff(lvl, mt, kt, lane)) = p;
    }
}

// ---------------- weight split: W[k][j] f32 -> B-fragment order (2-level f16) ----------------
__global__ __launch_bounds__(256) void wsplit_kernel(const float* __restrict__ Wx,
                                                     const float* __restrict__ Wh,
                                                     const float* __restrict__ Wattn,
                                                     unsigned short* __restrict__ Bf) {
    __shared__ float tile[32][33];
    int k0 = blockIdx.x * 32, j0 = blockIdx.y * 32;
    int t = threadIdx.x;
    int rl = t >> 3, c4 = (t & 7) * 4;
    int seg = k0 >> 10;
    const float* W = (seg == 0) ? Wx : (seg == 1) ? Wh : Wattn;
    const float4 v = *reinterpret_cast<const float4*>(W + (size_t)((k0 & 1023) + rl) * FOURH + j0 + c4);
    tile[rl][c4 + 0] = v.x; tile[rl][c4 + 1] = v.y; tile[rl][c4 + 2] = v.z; tile[rl][c4 + 3] = v.w;
    __syncthreads();
    int jl = t >> 3, k4 = (t & 7) * 4;
    unsigned short s[4][2];
#pragma unroll
    for (int i = 0; i < 4; ++i) split2(tile[k4 + i][jl], s[i][0], s[i][1]);
    int j = j0 + jl;
    int kg = k0 + k4;
    int ct = j >> 5, kt = kg >> 4;
    int lane = (j & 31) + 32 * ((kg >> 3) & 1);
    int sub = kg & 7;   // 0 or 4
#pragma unroll
    for (int lvl = 0; lvl < 2; ++lvl) {
        uint2 p;
        p.x = (unsigned)s[0][lvl] | ((unsigned)s[1][lvl] << 16);
        p.y = (unsigned)s[2][lvl] | ((unsigned)s[3][lvl] << 16);
        *reinterpret_cast<uint2*>(Bf + boff(lvl, ct, kt, lane) + sub) = p;
    }
}

// ---------------- shared device phases (512 threads) ----------------
__device__ __forceinline__ void attn_phase(const float* __restrict__ A, int n, int tid,
                                           const float* hsh, float* ash, float* red2) {
    int lane = tid & 63, wave = tid >> 6;   // 8 waves
    const float* An = A + (size_t)n * HH * 16;
    float areg[2][16];
    float part[16];
#pragma unroll
    for (int k = 0; k < 16; ++k) part[k] = 0.f;
#pragma unroll
    for (int i = 0; i < 2; ++i) {
        int hh = tid + i * 512;
        float hv = hsh[hh];
        const float* ap = An + (size_t)hh * 16;
#pragma unroll
        for (int k = 0; k < 16; ++k) {
            float av = ap[k];
            areg[i][k] = av;
            part[k] += hv * av;
        }
    }
#pragma unroll
    for (int k = 0; k < 16; ++k) {
        float v = part[k];
#pragma unroll
        for (int off = 32; off > 0; off >>= 1) v += __shfl_down(v, off);
        if (lane == 0) red2[wave * 16 + k] = v;
    }
    __syncthreads();
    float w[16];
    float mx = -1e30f;
#pragma unroll
    for (int k = 0; k < 16; ++k) {
        float s = 0.f;
#pragma unroll
        for (int q = 0; q < 8; ++q) s += red2[q * 16 + k];
        s *= 0.03125f;
        w[k] = s;
        mx = fmaxf(mx, s);
    }
    float sum = 0.f;
#pragma unroll
    for (int k = 0; k < 16; ++k) {
        w[k] = expf(w[k] - mx);
        sum += w[k];
    }
    float inv = 1.0f / sum;
#pragma unroll
    for (int k = 0; k < 16; ++k) w[k] *= inv;
#pragma unroll
    for (int i = 0; i < 2; ++i) {
        float s = 0.f;
#pragma unroll
        for (int k = 0; k < 16; ++k) s += areg[i][k] * w[k];
        ash[tid + i * 512] = s;
    }
}

// 3-way-parallel frag writes: seg 0 -> h, seg 1 -> attn, seg 2 -> x_{tnext}
__device__ __forceinline__ void write_state_frags(unsigned short* __restrict__ Af,
                                                  const float* __restrict__ x,
                                                  const float* hsh, const float* ash,
                                                  int n, int tnext, int tid) {
    int seg = tid >> 7;          // 0..3
    int k8 = (tid & 127) * 8;
    float v[8];
    if (seg == 0) {
#pragma unroll
        for (int i = 0; i < 8; ++i) v[i] = hsh[k8 + i];
        write_frag8(Af, n, 1024 + k8, v);
    } else if (seg == 1) {
#pragma unroll
        for (int i = 0; i < 8; ++i) v[i] = ash[k8 + i];
        write_frag8(Af, n, 2048 + k8, v);
    } else if (seg == 2 && tnext < TT) {
        const f32x4v* xp = reinterpret_cast<const f32x4v*>(x + ((size_t)n * TT + tnext) * DD + k8);
        f32x4v x0 = __builtin_nontemporal_load(xp);
        f32x4v x1 = __builtin_nontemporal_load(xp + 1);
        v[0] = x0[0]; v[1] = x0[1]; v[2] = x0[2]; v[3] = x0[3];
        v[4] = x1[0]; v[5] = x1[1]; v[6] = x1[2]; v[7] = x1[3];
        write_frag8(Af, n, k8, v);
    }
}

// ---------------- init ----------------
__global__ __launch_bounds__(512) void initk(const float* __restrict__ A,
                                             const float* __restrict__ x,
                                             float* __restrict__ c,
                                             unsigned short* __restrict__ Af) {
    int n = blockIdx.x, tid = threadIdx.x;
    __shared__ float hsh[HH], ash[HH];
    __shared__ float red2[128];
#pragma unroll
    for (int i = 0; i < 2; ++i) {
        int hh = tid + i * 512;
        const float* ap = A + ((size_t)n * HH + hh) * 16;
        float s = 0.f;
#pragma unroll
        for (int k = 0; k < 16; ++k) s += ap[k];
        s *= (1.0f / 16.0f);
        c[(size_t)n * HH + hh] = s;
        hsh[hh] = s;
    }
    __syncthreads();
    attn_phase(A, n, tid, hsh, ash, red2);
    __syncthreads();
    write_state_frags(Af, x, hsh, ash, n, 0, tid);
}

// ---------------- MFMA GEMM: depth-3 LDS, ONE barrier per chunk (R12-verified loop) ----
// grid 256 = 64 colb x 4 z; 512 thr = 8 waves (4 wm x 2 wn); M=256, N=64, K=768 per block
// chunk = 2 kt; 40 frags of 1KB (A: 32, B: 8). Buffers rotate mod 3 (120 KB LDS).
// Top-of-chunk barrier both publishes chunk cc AND proves buffer (cc-1)%3 is free.
#define KTPB 48
#define NCHUNK 24                 // KTPB / 2
#define BUFS 20480                // 40 * 512 shorts = 40 KB per buffer

#define STAGE(bidx, cc)                                                                        \
    {                                                                                          \
        _Pragma("unroll") for (int j = 0; j < 5; ++j) {                                        \
            __builtin_amdgcn_global_load_lds(                                                  \
                (const __attribute__((address_space(1))) unsigned int*)(sb[j] + (size_t)(cc) * 1024), \
                (__attribute__((address_space(3))) unsigned int*)&Bsm[(bidx)][ldsoff[j]],      \
                16, 0, 0);                                                                     \
        }                                                                                      \
    }

__global__ __launch_bounds__(512) void gemm_mfma(const unsigned short* __restrict__ Af,
                                                 const unsigned short* __restrict__ Bf,
                                                 float* __restrict__ apart) {
    __shared__ __align__(16) unsigned short Bsm[3][BUFS];   // 3 x 40 KB
    int tid = threadIdx.x;
    int l = tid & 63, w = tid >> 6;       // 8 waves: 4 wm x 2 wn
    int wm = w & 3, wn = w >> 2;
    int bid = blockIdx.x;
    int id = ((bid & 7) << 5) + (bid >> 3);   // XCD-chunked bijective swizzle (256 % 8 == 0)
    int colb = id & 63, z = id >> 6;
    int kt0 = z * KTPB;

    // staging assignment: thread handles frag ids f = w + 8j (wave-uniform), lane = l
    const unsigned short* sb[5];
    int ldsoff[5];
#pragma unroll
    for (int j = 0; j < 5; ++j) {
        int f = w + 8 * j;
        if (f < 32) {
            int ktc = f >> 4, lvl = (f >> 3) & 1, mt = f & 7;
            sb[j] = Af + aoff(lvl, mt, kt0 + ktc, l);
        } else {
            int g = f - 32;
            int ktc = g >> 2, lvl = (g >> 1) & 1, ct = g & 1;
            sb[j] = Bf + boff(lvl, colb * 2 + ct, kt0 + ktc, l);
        }
        ldsoff[j] = f * 512;
    }

    f32x16 accH[2] = {};
    f32x16 accM[2] = {};

    STAGE(0, 0)
    STAGE(1, 1)

    int cb = 0;                            // buffer holding chunk cc
    for (int cc = 0; cc < NCHUNK; ++cc) {
        if (cc + 1 < NCHUNK) { asm volatile("s_waitcnt vmcnt(5)" ::: "memory"); }
        else                 { asm volatile("s_waitcnt vmcnt(0)" ::: "memory"); }
        __builtin_amdgcn_sched_barrier(0);
        __builtin_amdgcn_s_barrier();      // chunk cc visible AND buffer (cc-1)%3 free
        __builtin_amdgcn_sched_barrier(0);
        if (cc + 2 < NCHUNK) {
            int tb = cb + 2; if (tb >= 3) tb -= 3;   // == (cc-1)%3
            STAGE(tb, cc + 2)
        }

        const unsigned short* base = &Bsm[cb][0];
        __builtin_amdgcn_s_setprio(1);
#pragma unroll
        for (int ktc = 0; ktc < 2; ++ktc) {
            const unsigned short* bp = base + (size_t)(32 + ktc * 4 + wn) * 512 + l * 8;   // lvl stride 2*512
            f16x8 b0 = *reinterpret_cast<const f16x8*>(bp);
            f16x8 b1 = *reinterpret_cast<const f16x8*>(bp + 1024);
            const unsigned short* ap0 = base + (size_t)(ktc * 16 + wm * 2) * 512 + l * 8;
            f16x8 a0m0 = *reinterpret_cast<const f16x8*>(ap0);
            f16x8 a0m1 = *reinterpret_cast<const f16x8*>(ap0 + 512);
            f16x8 a1m0 = *reinterpret_cast<const f16x8*>(ap0 + 8 * 512);
            f16x8 a1m1 = *reinterpret_cast<const f16x8*>(ap0 + 9 * 512);
            accH[0] = __builtin_amdgcn_mfma_f32_32x32x16_f16(a0m0, b0, accH[0], 0, 0, 0);
            accM[0] = __builtin_amdgcn_mfma_f32_32x32x16_f16(a0m0, b1, accM[0], 0, 0, 0);
            accM[0] = __builtin_amdgcn_mfma_f32_32x32x16_f16(a1m0, b0, accM[0], 0, 0, 0);
            accH[1] = __builtin_amdgcn_mfma_f32_32x32x16_f16(a0m1, b0, accH[1], 0, 0, 0);
            accM[1] = __builtin_amdgcn_mfma_f32_32x32x16_f16(a0m1, b1, accM[1], 0, 0, 0);
            accM[1] = __builtin_amdgcn_mfma_f32_32x32x16_f16(a1m1, b0, accM[1], 0, 0, 0);
        }
        __builtin_amdgcn_s_setprio(0);
        cb = (cb + 1 == 3) ? 0 : cb + 1;
    }

    // epilogue: combine hi + mid/2048; nontemporal stores keep apart out of L3
    float* plane = apart + (size_t)z * P1;
    int col = colb * 64 + wn * 32 + (l & 31);
#pragma unroll
    for (int mi = 0; mi < 2; ++mi) {
        int rbase = (wm * 2 + mi) * 32 + (l >> 5) * 4;
#pragma unroll
        for (int r = 0; r < 16; ++r) {
            int row = rbase + (r & 3) + 8 * (r >> 2);
            __builtin_nontemporal_store(accH[mi][r] + accM[mi][r] * INV_SPLIT,
                                        &plane[(size_t)row * FOURH + col]);
        }
    }
}

// ---------------- pointwise: gates + LSTM + attn + frag writes (512 thr, nt loads/stores) ----------------
__global__ __launch_bounds__(512) void pointwise(const float* __restrict__ apart,
                                                 const float* __restrict__ bias,
                                                 const float* __restrict__ A,
                                                 const float* __restrict__ x,
                                                 float* __restrict__ c,
                                                 float* __restrict__ out,
                                                 unsigned short* __restrict__ Af, int t) {
    int n = blockIdx.x, tid = threadIdx.x;
    __shared__ float hsh[HH], ash[HH];
    __shared__ float red2[128];
    const float* ap = apart + (size_t)n * FOURH;
    int hh2 = tid * 2;
    f32x2v g2[4];
#pragma unroll
    for (int g = 0; g < 4; ++g) {
        int j = g * 1024 + hh2;
        f32x2v s = *reinterpret_cast<const f32x2v*>(bias + j);
#pragma unroll
        for (int zz = 0; zz < NZ; ++zz) {
            f32x2v p = __builtin_nontemporal_load(
                reinterpret_cast<const f32x2v*>(ap + (size_t)zz * P1 + j));
            s[0] += p[0]; s[1] += p[1];
        }
        g2[g] = s;
    }
    f32x2v cold = *reinterpret_cast<const f32x2v*>(c + (size_t)n * HH + hh2);
    f32x2v hn2;
    {
        float ig = 1.f / (1.f + expf(-g2[0][0]));
        float fg = 1.f / (1.f + expf(-g2[1][0]));
        float og = 1.f / (1.f + expf(-g2[2][0]));
        float gg = tanhf(g2[3][0]);
        float cn = fg * cold[0] + ig * gg;
        hn2[0] = og * tanhf(cn);
        cold[0] = cn;
    }
    {
        float ig = 1.f / (1.f + expf(-g2[0][1]));
        float fg = 1.f / (1.f + expf(-g2[1][1]));
        float og = 1.f / (1.f + expf(-g2[2][1]));
        float gg = tanhf(g2[3][1]);
        float cn = fg * cold[1] + ig * gg;
        hn2[1] = og * tanhf(cn);
        cold[1] = cn;
    }
    *reinterpret_cast<f32x2v*>(c + (size_t)n * HH + hh2) = cold;
    __builtin_nontemporal_store(hn2, reinterpret_cast<f32x2v*>(out + ((size_t)n * TT + t) * HH + hh2));
    *reinterpret_cast<f32x2v*>(&hsh[hh2]) = hn2;
    __syncthreads();
    attn_phase(A, n, tid, hsh, ash, red2);
    __syncthreads();
    write_state_frags(Af, x, hsh, ash, n, t + 1, tid);
}

extern "C" void kernel_launch(void* const* d_in, const int* in_sizes, int n_in,
                              void* d_out, int out_size, void* d_ws, size_t ws_size,
                              hipStream_t stream) {
    const float* x     = (const float*)d_in[0];
    const float* A     = (const float*)d_in[1];
    const float* Wx    = (const float*)d_in[2];
    const float* Wh    = (const float*)d_in[3];
    const float* Wattn = (const float*)d_in[4];
    const float* b     = (const float*)d_in[5];
    float* out = (float*)d_out;

    unsigned short* Bf = (unsigned short*)d_ws;        // 2*BF_LVL f16 = 50.3 MB
    unsigned short* Af = Bf + 2 * BF_LVL;              // 2*AF_LVL f16 = 3.1 MB
    float* apart = (float*)(Af + 2 * AF_LVL);          // 4 * P1 f32 = 16 MB
    float* c = apart + (size_t)NZ * P1;                // 1 MB

    wsplit_kernel<<<dim3(KTOT / 32, FOURH / 32), 256, 0, stream>>>(Wx, Wh, Wattn, Bf);
    initk<<<NB, 512, 0, stream>>>(A, x, c, Af);

    for (int t = 0; t < TT; ++t) {
        gemm_mfma<<<256, 512, 0, stream>>>(Af, Bf, apart);
        pointwise<<<NB, 512, 0, stream>>>(apart, b, A, x, c, out, Af, t);
    }
}